// Round 4
// baseline (412.188 us; speedup 1.0000x reference)
//
#include <hip/hip_runtime.h>
#include <cstdint>
#include <cstddef>

// SOM BMU: dists[b,m] = ||x[b] - W[:,m] + eps||, argmin/min over m.
//   sq = rowTerm[b] + colTerm[m] - 2*dot(x[b],W[:,m]) + D*eps^2
// dot via split-precision f16 MFMA (xh.wh + xh.wl + xl.wh, ~2^-22 rel err).
// 32x32x16 MFMA; FRAGMENT-MAJOR LDS layout: slot(row,ch) =
//   (row>>5)*128 + (ch>>1)*64 + (ch&1)*32 + (row&31)
// so every MFMA fragment ds_read_b128 is base + lane*16 (conflict-free),
// and global_load_lds staging inverts the map on the global address side.
// Argmin via packed u64 key (dist_bits<<32 | m) + atomicMin.

#define B_  2048
#define D_  1024
#define M_  16384
#define EPS_ 1e-6f

typedef _Float16 v8h  __attribute__((ext_vector_type(8)));
typedef _Float16 v4h  __attribute__((ext_vector_type(4)));
typedef float    v16f __attribute__((ext_vector_type(16)));

static __device__ __forceinline__ unsigned long long umin64(unsigned long long a,
                                                            unsigned long long b) {
    return a < b ? a : b;
}

#define GLDS16(g, l)                                                            \
    __builtin_amdgcn_global_load_lds(                                           \
        (const __attribute__((address_space(1))) void*)(g),                     \
        (__attribute__((address_space(3))) void*)(l), 16, 0, 0)

// ---------- convert x -> xh,xl (f16) + rowTerm ----------
__global__ void xconv(const float* __restrict__ x,
                      _Float16* __restrict__ xh, _Float16* __restrict__ xl,
                      float* __restrict__ rowTerm) {
    int b = blockIdx.x;
    int t = threadIdx.x;  // 256
    const float4 v = *(const float4*)(x + (size_t)b * D_ + t * 4);
    v4h h, l;
    float acc = 0.f;
    float vv[4] = {v.x, v.y, v.z, v.w};
    #pragma unroll
    for (int e = 0; e < 4; ++e) {
        _Float16 hi = (_Float16)vv[e];
        float lo = vv[e] - (float)hi;
        h[e] = hi; l[e] = (_Float16)lo;
        acc += vv[e] * vv[e] + 2.0f * EPS_ * vv[e];
    }
    *(v4h*)(xh + (size_t)b * D_ + t * 4) = h;
    *(v4h*)(xl + (size_t)b * D_ + t * 4) = l;
    for (int off = 32; off; off >>= 1) acc += __shfl_down(acc, off, 64);
    __shared__ float s[4];
    if ((t & 63) == 0) s[t >> 6] = acc;
    __syncthreads();
    if (t == 0) rowTerm[b] = s[0] + s[1] + s[2] + s[3];
}

// ---------- convert+transpose W -> Wth,Wtl [m][d] + colTerm ----------
// 64x64 tile; output writes: 4 lanes cover one row's 128 B contiguously
// (full 64B-line writes, no RMW amplification).
__global__ void wconv(const float* __restrict__ W,
                      _Float16* __restrict__ wth, _Float16* __restrict__ wtl,
                      float* __restrict__ colTerm) {
    __shared__ float tile[64][65];
    const int t = threadIdx.x;
    const int m0 = blockIdx.x * 64;
    const int d0 = blockIdx.y * 64;
    const int dloc = t >> 4, mq = (t & 15) * 4;
    #pragma unroll
    for (int s = 0; s < 4; ++s) {
        float4 v = *(const float4*)(W + (size_t)(d0 + dloc + 16 * s) * M_ + m0 + mq);
        tile[dloc + 16 * s][mq + 0] = v.x;
        tile[dloc + 16 * s][mq + 1] = v.y;
        tile[dloc + 16 * s][mq + 2] = v.z;
        tile[dloc + 16 * s][mq + 3] = v.w;
    }
    __syncthreads();
    const int mloc = t >> 2;
    const int dc = (t & 3) * 16;
    v8h h0, l0, h1, l1;
    float acc = 0.f;
    #pragma unroll
    for (int e = 0; e < 8; ++e) {
        float v = tile[dc + e][mloc];
        _Float16 hi = (_Float16)v;
        h0[e] = hi; l0[e] = (_Float16)(v - (float)hi);
        acc += v * v - 2.0f * EPS_ * v;
    }
    #pragma unroll
    for (int e = 0; e < 8; ++e) {
        float v = tile[dc + 8 + e][mloc];
        _Float16 hi = (_Float16)v;
        h1[e] = hi; l1[e] = (_Float16)(v - (float)hi);
        acc += v * v - 2.0f * EPS_ * v;
    }
    _Float16* oh = wth + (size_t)(m0 + mloc) * D_ + d0 + dc;
    _Float16* ol = wtl + (size_t)(m0 + mloc) * D_ + d0 + dc;
    *(v8h*)oh = h0; *(v8h*)(oh + 8) = h1;
    *(v8h*)ol = l0; *(v8h*)(ol + 8) = l1;
    acc += __shfl_xor(acc, 1, 64);
    acc += __shfl_xor(acc, 2, 64);
    if ((t & 3) == 0) atomicAdd(&colTerm[m0 + mloc], acc);
}

// ---------- main MFMA distance GEMM + argmin ----------
// 128x128 tile, 4 waves (2x2 of 64x64), BK=32, 32x32x16 f16 MFMA.
__global__ __launch_bounds__(256, 2) void som_mfma(
    const _Float16* __restrict__ xh, const _Float16* __restrict__ xl,
    const _Float16* __restrict__ wth, const _Float16* __restrict__ wtl,
    const float* __restrict__ rowTerm, const float* __restrict__ colTerm,
    unsigned long long* __restrict__ keys)
{
    __shared__ __align__(16) _Float16 smem[16384];  // 32 KB: Ah|Al|Bh|Bl
    _Float16* Ah = smem;
    _Float16* Al = smem + 4096;
    _Float16* Bh = smem + 8192;
    _Float16* Bl = smem + 12288;

    const int t  = threadIdx.x;
    const int rb = blockIdx.x * 128;   // row-tile in x: concurrent blocks share B
    const int cb = blockIdx.y * 128;
    const int L  = t & 63, w = t >> 6;
    const int wro = (w >> 1) * 64, wco = (w & 1) * 64;
    const int l31 = L & 31, q = L >> 5;

    // staging: slot s = n*256 + t  (n = call index 0/1)
    //   row(s) = (s>>7)*32 + (s&31); ch(s) = ((s>>6)&1)*2 + ((s>>5)&1)
    int s0 = t, s1 = t + 256;
    const int row0 = ((s0 >> 7) << 5) + (s0 & 31);
    const int ch0  = (((s0 >> 6) & 1) << 1) + ((s0 >> 5) & 1);
    const int row1 = ((s1 >> 7) << 5) + (s1 & 31);
    const int ch1  = (((s1 >> 6) & 1) << 1) + ((s1 >> 5) & 1);
    const size_t aoff1 = (size_t)(rb + row0) * 2048 + ch0 * 16;
    const size_t aoff2 = (size_t)(rb + row1) * 2048 + ch1 * 16;
    const size_t boff1 = (size_t)(cb + row0) * 2048 + ch0 * 16;
    const size_t boff2 = (size_t)(cb + row1) * 2048 + ch1 * 16;
    const int lds1 = (t & 192) * 16;          // wave-uniform; HW adds lane*16
    const int lds2 = lds1 + 4096;
    const char* pxh = (const char*)xh;
    const char* pxl = (const char*)xl;
    const char* pwh = (const char*)wth;
    const char* pwl = (const char*)wtl;

    v16f acc[2][2];
    #pragma unroll
    for (int i = 0; i < 2; ++i)
        #pragma unroll
        for (int j = 0; j < 2; ++j)
            #pragma unroll
            for (int r = 0; r < 16; ++r) acc[i][j][r] = 0.f;

    // fragment LDS indices (f16 units): frag (rgrp,h) -> ((rgrp*2+h)*64 + L)*8
    int ia[2][2], ib[2][2];
    #pragma unroll
    for (int ti = 0; ti < 2; ++ti) {
        int rgA = (wro >> 5) + ti;   // 0..3
        int rgB = (wco >> 5) + ti;
        #pragma unroll
        for (int h = 0; h < 2; ++h) {
            ia[ti][h] = ((rgA * 2 + h) * 64 + L) * 8;
            ib[ti][h] = ((rgB * 2 + h) * 64 + L) * 8;
        }
    }

    for (int kb = 0; kb < 2048; kb += 64) {  // 64 B = BK (32 f16)
        __syncthreads();
        GLDS16(pxh + aoff1 + kb, (char*)Ah + lds1);
        GLDS16(pxh + aoff2 + kb, (char*)Ah + lds2);
        GLDS16(pxl + aoff1 + kb, (char*)Al + lds1);
        GLDS16(pxl + aoff2 + kb, (char*)Al + lds2);
        GLDS16(pwh + boff1 + kb, (char*)Bh + lds1);
        GLDS16(pwh + boff2 + kb, (char*)Bh + lds2);
        GLDS16(pwl + boff1 + kb, (char*)Bl + lds1);
        GLDS16(pwl + boff2 + kb, (char*)Bl + lds2);
        __syncthreads();

        v8h fah[2][2], fal[2][2], fbh[2][2], fbl[2][2];
        #pragma unroll
        for (int ti = 0; ti < 2; ++ti)
            #pragma unroll
            for (int h = 0; h < 2; ++h) {
                fah[ti][h] = *(const v8h*)(Ah + ia[ti][h]);
                fal[ti][h] = *(const v8h*)(Al + ia[ti][h]);
                fbh[ti][h] = *(const v8h*)(Bh + ib[ti][h]);
                fbl[ti][h] = *(const v8h*)(Bl + ib[ti][h]);
            }
        #pragma unroll
        for (int ti = 0; ti < 2; ++ti)
            #pragma unroll
            for (int tj = 0; tj < 2; ++tj)
                #pragma unroll
                for (int h = 0; h < 2; ++h) {
                    acc[ti][tj] = __builtin_amdgcn_mfma_f32_32x32x16_f16(
                        fah[ti][h], fbh[tj][h], acc[ti][tj], 0, 0, 0);
                    acc[ti][tj] = __builtin_amdgcn_mfma_f32_32x32x16_f16(
                        fah[ti][h], fbl[tj][h], acc[ti][tj], 0, 0, 0);
                    acc[ti][tj] = __builtin_amdgcn_mfma_f32_32x32x16_f16(
                        fal[ti][h], fbh[tj][h], acc[ti][tj], 0, 0, 0);
                }
    }

    // epilogue: 32x32 C/D layout col=lane&31, row=(reg&3)+8*(reg>>2)+4*(lane>>5)
    float cT[2];
    #pragma unroll
    for (int tj = 0; tj < 2; ++tj) cT[tj] = colTerm[cb + wco + tj * 32 + l31];
    const float de2 = (float)D_ * EPS_ * EPS_;
    #pragma unroll
    for (int ti = 0; ti < 2; ++ti) {
        #pragma unroll
        for (int reg = 0; reg < 16; ++reg) {
            int row_g = rb + wro + ti * 32 + (reg & 3) + 8 * (reg >> 2) + 4 * q;
            float rt = rowTerm[row_g];
            unsigned long long best = ~0ull;
            #pragma unroll
            for (int tj = 0; tj < 2; ++tj) {
                float sq = rt + cT[tj] - 2.0f * acc[ti][tj][reg] + de2;
                sq = fmaxf(sq, 0.0f);
                float dist = sqrtf(sq);
                unsigned long long key =
                    ((unsigned long long)__float_as_uint(dist) << 32) |
                    (unsigned int)(cb + wco + tj * 32 + l31);
                best = umin64(best, key);
            }
            #pragma unroll
            for (int m = 1; m <= 16; m <<= 1) {
                unsigned long long o =
                    (unsigned long long)__shfl_xor((long long)best, m, 64);
                best = umin64(best, o);
            }
            if (l31 == 0) atomicMin(&keys[row_g], best);
        }
    }
}

// ---------- fallback fp32 path (used only if ws too small) ----------
__global__ void row_stats(const float* __restrict__ x, float* __restrict__ rowTerm) {
    int b = blockIdx.x;
    const float* xr = x + (size_t)b * D_;
    int t = threadIdx.x;
    float acc = 0.f;
    for (int i = t; i < D_; i += 256) {
        float v = xr[i];
        acc += v * v + 2.0f * EPS_ * v;
    }
    for (int off = 32; off; off >>= 1) acc += __shfl_down(acc, off, 64);
    __shared__ float s[4];
    if ((t & 63) == 0) s[t >> 6] = acc;
    __syncthreads();
    if (t == 0) rowTerm[b] = s[0] + s[1] + s[2] + s[3];
}

__global__ void col_stats(const float* __restrict__ w, float* __restrict__ colTerm) {
    int m = blockIdx.x * 256 + threadIdx.x;
    int d0 = blockIdx.y * 64;
    const float* p = w + (size_t)d0 * M_ + m;
    float acc = 0.f;
    #pragma unroll 8
    for (int d = 0; d < 64; ++d) {
        float v = p[(size_t)d * M_];
        acc += v * v - 2.0f * EPS_ * v;
    }
    atomicAdd(&colTerm[m], acc);
}

__global__ __launch_bounds__(256, 2) void som_gemm(
    const float* __restrict__ A, const float* __restrict__ Wt,
    const float* __restrict__ rowTerm, const float* __restrict__ colTerm,
    unsigned long long* __restrict__ keys)
{
    __shared__ float As[8][128];
    __shared__ float Bs[8][128];
    const int t  = threadIdx.x;
    const int rb = blockIdx.y * 128;
    const int cb = blockIdx.x * 128;
    const int tx = t & 15;
    const int ty = t >> 4;
    float acc[8][8];
    #pragma unroll
    for (int i = 0; i < 8; ++i)
        #pragma unroll
        for (int j = 0; j < 8; ++j) acc[i][j] = 0.f;
    const int la_row = t >> 1, la_k = (t & 1) * 4;
    const int lb_k = t >> 5, lb_n = (t & 31) * 4;
    const float* Aptr = A + (size_t)(rb + la_row) * D_ + la_k;
    const float* Bptr = Wt + (size_t)lb_k * M_ + cb + lb_n;
    for (int k0 = 0; k0 < D_; k0 += 8) {
        float4 av = *(const float4*)(Aptr + k0);
        float4 bv = *(const float4*)(Bptr + (size_t)k0 * M_);
        __syncthreads();
        As[la_k + 0][la_row] = av.x;
        As[la_k + 1][la_row] = av.y;
        As[la_k + 2][la_row] = av.z;
        As[la_k + 3][la_row] = av.w;
        *(float4*)&Bs[lb_k][lb_n] = bv;
        __syncthreads();
        #pragma unroll
        for (int k = 0; k < 8; ++k) {
            float a[8], b[8];
            #pragma unroll
            for (int i = 0; i < 8; ++i) a[i] = As[k][ty * 8 + i];
            #pragma unroll
            for (int j = 0; j < 8; ++j) b[j] = Bs[k][tx * 8 + j];
            #pragma unroll
            for (int i = 0; i < 8; ++i)
                #pragma unroll
                for (int j = 0; j < 8; ++j) acc[i][j] += a[i] * b[j];
        }
    }
    float rT[8], cT[8];
    #pragma unroll
    for (int i = 0; i < 8; ++i) rT[i] = rowTerm[rb + ty * 8 + i];
    #pragma unroll
    for (int j = 0; j < 8; ++j) cT[j] = colTerm[cb + tx * 8 + j];
    const float de2 = (float)D_ * EPS_ * EPS_;
    #pragma unroll
    for (int i = 0; i < 8; ++i) {
        unsigned long long best = ~0ull;
        #pragma unroll
        for (int j = 0; j < 8; ++j) {
            float sq = rT[i] + cT[j] - 2.0f * acc[i][j] + de2;
            sq = fmaxf(sq, 0.0f);
            float dist = sqrtf(sq);
            unsigned long long key =
                ((unsigned long long)__float_as_uint(dist) << 32) |
                (unsigned int)(cb + tx * 8 + j);
            best = umin64(best, key);
        }
        #pragma unroll
        for (int msk = 1; msk <= 8; msk <<= 1) {
            unsigned long long o = __shfl_xor((long long)best, msk, 64);
            best = umin64(best, (unsigned long long)o);
        }
        if (tx == 0) atomicMin(&keys[rb + ty * 8 + i], best);
    }
}

// ---------- finalize: 8 blocks of 256 rows ----------
__global__ void finalize(const unsigned long long* __restrict__ keys,
                         const float* __restrict__ loc,
                         float* __restrict__ out)
{
    int t = threadIdx.x;
    int r = blockIdx.x * 256 + t;
    unsigned long long k = keys[r];
    unsigned int idx = (unsigned int)(k & 0xFFFFFFFFu);
    float dist = __uint_as_float((unsigned int)(k >> 32));
    out[r] = (float)idx;
    out[B_ + 2 * r]     = loc[2 * idx];
    out[B_ + 2 * r + 1] = loc[2 * idx + 1];
    float sum = dist;
    for (int off = 32; off; off >>= 1) sum += __shfl_down(sum, off, 64);
    __shared__ float s[4];
    if ((t & 63) == 0) s[t >> 6] = sum;
    __syncthreads();
    if (t == 0) atomicAdd(&out[3 * B_], (s[0] + s[1] + s[2] + s[3]) / (float)B_);
}

extern "C" void kernel_launch(void* const* d_in, const int* in_sizes, int n_in,
                              void* d_out, int out_size, void* d_ws, size_t ws_size,
                              hipStream_t stream)
{
    const float* x   = (const float*)d_in[0];
    const float* w   = (const float*)d_in[1];
    const float* loc = (const float*)d_in[2];
    float* out = (float*)d_out;

    char* ws = (char*)d_ws;
    unsigned long long* keys = (unsigned long long*)ws;   // 16 KB
    float* rowTerm = (float*)(ws + (16 << 10));           //  8 KB
    float* colTerm = (float*)(ws + (24 << 10));           // 64 KB
    _Float16* xh  = (_Float16*)(ws + (1ull << 20));       //  4 MB
    _Float16* xl  = (_Float16*)(ws + (5ull << 20));       //  4 MB
    _Float16* wth = (_Float16*)(ws + (9ull << 20));       // 32 MB
    _Float16* wtl = (_Float16*)(ws + (41ull << 20));      // 32 MB
    const size_t NEED = 73ull << 20;

    hipMemsetAsync(keys, 0xFF, B_ * sizeof(unsigned long long), stream);
    hipMemsetAsync(colTerm, 0, M_ * sizeof(float), stream);
    hipMemsetAsync(out + 3 * B_, 0, sizeof(float), stream);

    if (ws_size >= NEED) {
        xconv<<<B_, 256, 0, stream>>>(x, xh, xl, rowTerm);
        wconv<<<dim3(M_ / 64, D_ / 64), 256, 0, stream>>>(w, wth, wtl, colTerm);
        som_mfma<<<dim3(B_ / 128, M_ / 128), 256, 0, stream>>>(
            xh, xl, wth, wtl, rowTerm, colTerm, keys);
    } else {
        row_stats<<<B_, 256, 0, stream>>>(x, rowTerm);
        col_stats<<<dim3(M_ / 256, D_ / 64), 256, 0, stream>>>(w, colTerm);
        som_gemm<<<dim3(M_ / 128, B_ / 128), 256, 0, stream>>>(
            x, w, rowTerm, colTerm, keys);
    }
    finalize<<<8, 256, 0, stream>>>(keys, loc, out);
}

// Round 5
// 402.092 us; speedup vs baseline: 1.0251x; 1.0251x over previous
//
#include <hip/hip_runtime.h>
#include <cstdint>
#include <cstddef>

// SOM BMU: dists[b,m] = ||x[b] - W[:,m] + eps||, argmin/min over m.
//   sq = rowTerm[b] + colTerm[m] - 2*dot(x[b],W[:,m]) + D*eps^2
// dot via split-precision f16 MFMA (xh.wh + xh.wl + xl.wh, ~2^-22 rel err).
// 16x16x32 MFMA (more MFMA-cyc per LDS-byte than 32x32x16 -> higher util
// under the LDS-BW bound measured in R4). FRAGMENT-MAJOR LDS layout:
//   slot s (16B) holds (row=(s>>6)*16+(s&15), kchunk=(s>>4)&3)
// so each fragment ds_read_b128 is base + lane*16 (conflict-free); staging
// keeps slot=t LDS destinations, remapping only the global source per lane.
// Argmin via packed u64 key (dist_bits<<32 | m) + atomicMin.

#define B_  2048
#define D_  1024
#define M_  16384
#define EPS_ 1e-6f

typedef _Float16 v8h __attribute__((ext_vector_type(8)));
typedef _Float16 v4h __attribute__((ext_vector_type(4)));
typedef float    v4f __attribute__((ext_vector_type(4)));

static __device__ __forceinline__ unsigned long long umin64(unsigned long long a,
                                                            unsigned long long b) {
    return a < b ? a : b;
}

#define GLDS16(g, l)                                                            \
    __builtin_amdgcn_global_load_lds(                                           \
        (const __attribute__((address_space(1))) void*)(g),                     \
        (__attribute__((address_space(3))) void*)(l), 16, 0, 0)

// ---------- convert x -> xh,xl (f16) + rowTerm ----------
__global__ void xconv(const float* __restrict__ x,
                      _Float16* __restrict__ xh, _Float16* __restrict__ xl,
                      float* __restrict__ rowTerm) {
    int b = blockIdx.x;
    int t = threadIdx.x;  // 256
    const float4 v = *(const float4*)(x + (size_t)b * D_ + t * 4);
    v4h h, l;
    float acc = 0.f;
    float vv[4] = {v.x, v.y, v.z, v.w};
    #pragma unroll
    for (int e = 0; e < 4; ++e) {
        _Float16 hi = (_Float16)vv[e];
        float lo = vv[e] - (float)hi;
        h[e] = hi; l[e] = (_Float16)lo;
        acc += vv[e] * vv[e] + 2.0f * EPS_ * vv[e];
    }
    *(v4h*)(xh + (size_t)b * D_ + t * 4) = h;
    *(v4h*)(xl + (size_t)b * D_ + t * 4) = l;
    for (int off = 32; off; off >>= 1) acc += __shfl_down(acc, off, 64);
    __shared__ float s[4];
    if ((t & 63) == 0) s[t >> 6] = acc;
    __syncthreads();
    if (t == 0) rowTerm[b] = s[0] + s[1] + s[2] + s[3];
}

// ---------- convert+transpose W -> Wth,Wtl [m][d] + colTerm ----------
// 64x64 tile; 4 lanes cover one output row's 128 B contiguously.
__global__ void wconv(const float* __restrict__ W,
                      _Float16* __restrict__ wth, _Float16* __restrict__ wtl,
                      float* __restrict__ colTerm) {
    __shared__ float tile[64][65];
    const int t = threadIdx.x;
    const int m0 = blockIdx.x * 64;
    const int d0 = blockIdx.y * 64;
    const int dloc = t >> 4, mq = (t & 15) * 4;
    #pragma unroll
    for (int s = 0; s < 4; ++s) {
        float4 v = *(const float4*)(W + (size_t)(d0 + dloc + 16 * s) * M_ + m0 + mq);
        tile[dloc + 16 * s][mq + 0] = v.x;
        tile[dloc + 16 * s][mq + 1] = v.y;
        tile[dloc + 16 * s][mq + 2] = v.z;
        tile[dloc + 16 * s][mq + 3] = v.w;
    }
    __syncthreads();
    const int mloc = t >> 2;
    const int dc = (t & 3) * 16;
    v8h h0, l0, h1, l1;
    float acc = 0.f;
    #pragma unroll
    for (int e = 0; e < 8; ++e) {
        float v = tile[dc + e][mloc];
        _Float16 hi = (_Float16)v;
        h0[e] = hi; l0[e] = (_Float16)(v - (float)hi);
        acc += v * v - 2.0f * EPS_ * v;
    }
    #pragma unroll
    for (int e = 0; e < 8; ++e) {
        float v = tile[dc + 8 + e][mloc];
        _Float16 hi = (_Float16)v;
        h1[e] = hi; l1[e] = (_Float16)(v - (float)hi);
        acc += v * v - 2.0f * EPS_ * v;
    }
    _Float16* oh = wth + (size_t)(m0 + mloc) * D_ + d0 + dc;
    _Float16* ol = wtl + (size_t)(m0 + mloc) * D_ + d0 + dc;
    *(v8h*)oh = h0; *(v8h*)(oh + 8) = h1;
    *(v8h*)ol = l0; *(v8h*)(ol + 8) = l1;
    acc += __shfl_xor(acc, 1, 64);
    acc += __shfl_xor(acc, 2, 64);
    if ((t & 3) == 0) atomicAdd(&colTerm[m0 + mloc], acc);
}

// ---------- main MFMA distance GEMM + argmin ----------
// 128x128 tile, 4 waves (2x2 of 64x64), BK=32, 16x16x32 f16 MFMA.
__global__ __launch_bounds__(256, 2) void som_mfma(
    const _Float16* __restrict__ xh, const _Float16* __restrict__ xl,
    const _Float16* __restrict__ wth, const _Float16* __restrict__ wtl,
    const float* __restrict__ rowTerm, const float* __restrict__ colTerm,
    unsigned long long* __restrict__ keys)
{
    __shared__ __align__(16) _Float16 smem[16384];  // 32 KB: Ah|Al|Bh|Bl
    _Float16* Ah = smem;
    _Float16* Al = smem + 4096;
    _Float16* Bh = smem + 8192;
    _Float16* Bl = smem + 12288;

    const int t  = threadIdx.x;
    const int rb = blockIdx.y * 128;   // R2 grid orientation (x = col-tile)
    const int cb = blockIdx.x * 128;
    const int L  = t & 63, w = t >> 6;
    const int wro = (w >> 1) * 64, wco = (w & 1) * 64;
    const int c16 = L & 15, kq = L >> 4;

    // staging: LDS slot s = n*256 + t; fragment-major meaning:
    //   row(s) = (s>>6)*16 + (s&15), ch(s) = (s>>4)&3
    const int row0 = ((t >> 6) << 4) + (t & 15);   // call 0: rgrp 0..3
    const int ch0  = (t >> 4) & 3;
    const size_t aoff1 = (size_t)(rb + row0) * 2048 + ch0 * 16;
    const size_t aoff2 = aoff1 + 64ull * 2048;     // call 1: rows +64, same ch
    const size_t boff1 = (size_t)(cb + row0) * 2048 + ch0 * 16;
    const size_t boff2 = boff1 + 64ull * 2048;
    const int lds1 = (t & 192) * 16;               // slot = t (HW adds lane*16)
    const int lds2 = lds1 + 4096;                  // slot = 256 + t
    const char* pxh = (const char*)xh;
    const char* pxl = (const char*)xl;
    const char* pwh = (const char*)wth;
    const char* pwl = (const char*)wtl;

    v4f acc[4][4];
    #pragma unroll
    for (int i = 0; i < 4; ++i)
        #pragma unroll
        for (int j = 0; j < 4; ++j) acc[i][j] = (v4f){0.f, 0.f, 0.f, 0.f};

    // fragment LDS f16-indices: group g reads slots g*64+L -> f16 g*512 + L*8
    int ia[4], ib[4];
    #pragma unroll
    for (int i = 0; i < 4; ++i) {
        ia[i] = ((wro >> 4) + i) * 512 + L * 8;
        ib[i] = ((wco >> 4) + i) * 512 + L * 8;
    }

    for (int kb = 0; kb < 2048; kb += 64) {  // 64 B = BK (32 f16)
        __syncthreads();
        GLDS16(pxh + aoff1 + kb, (char*)Ah + lds1);
        GLDS16(pxh + aoff2 + kb, (char*)Ah + lds2);
        GLDS16(pxl + aoff1 + kb, (char*)Al + lds1);
        GLDS16(pxl + aoff2 + kb, (char*)Al + lds2);
        GLDS16(pwh + boff1 + kb, (char*)Bh + lds1);
        GLDS16(pwh + boff2 + kb, (char*)Bh + lds2);
        GLDS16(pwl + boff1 + kb, (char*)Bl + lds1);
        GLDS16(pwl + boff2 + kb, (char*)Bl + lds2);
        __syncthreads();

        v8h ah[4], al4[4], bh[4], bl4[4];
        #pragma unroll
        for (int i = 0; i < 4; ++i) {
            ah[i]  = *(const v8h*)(Ah + ia[i]);
            al4[i] = *(const v8h*)(Al + ia[i]);
            bh[i]  = *(const v8h*)(Bh + ib[i]);
            bl4[i] = *(const v8h*)(Bl + ib[i]);
        }
        #pragma unroll
        for (int i = 0; i < 4; ++i)
            #pragma unroll
            for (int j = 0; j < 4; ++j) {
                acc[i][j] = __builtin_amdgcn_mfma_f32_16x16x32_f16(ah[i],  bh[j],  acc[i][j], 0, 0, 0);
                acc[i][j] = __builtin_amdgcn_mfma_f32_16x16x32_f16(ah[i],  bl4[j], acc[i][j], 0, 0, 0);
                acc[i][j] = __builtin_amdgcn_mfma_f32_16x16x32_f16(al4[i], bh[j],  acc[i][j], 0, 0, 0);
            }
    }

    // epilogue: C/D layout col=lane&15, row=(lane>>4)*4+reg  [verified m89/m91]
    float cT[4];
    #pragma unroll
    for (int j = 0; j < 4; ++j) cT[j] = colTerm[cb + wco + j * 16 + c16];
    const float de2 = (float)D_ * EPS_ * EPS_;
    #pragma unroll
    for (int i = 0; i < 4; ++i) {
        #pragma unroll
        for (int r = 0; r < 4; ++r) {
            int row_g = rb + wro + i * 16 + kq * 4 + r;
            float rt = rowTerm[row_g];
            unsigned long long best = ~0ull;
            #pragma unroll
            for (int j = 0; j < 4; ++j) {
                float sq = rt + cT[j] - 2.0f * acc[i][j][r] + de2;
                sq = fmaxf(sq, 0.0f);
                float dist = sqrtf(sq);
                unsigned long long key =
                    ((unsigned long long)__float_as_uint(dist) << 32) |
                    (unsigned int)(cb + wco + j * 16 + c16);
                best = umin64(best, key);
            }
            #pragma unroll
            for (int m = 1; m <= 8; m <<= 1) {
                unsigned long long o =
                    (unsigned long long)__shfl_xor((long long)best, m, 64);
                best = umin64(best, o);
            }
            if (c16 == 0) atomicMin(&keys[row_g], best);
        }
    }
}

// ---------- fallback fp32 path (used only if ws too small) ----------
__global__ void row_stats(const float* __restrict__ x, float* __restrict__ rowTerm) {
    int b = blockIdx.x;
    const float* xr = x + (size_t)b * D_;
    int t = threadIdx.x;
    float acc = 0.f;
    for (int i = t; i < D_; i += 256) {
        float v = xr[i];
        acc += v * v + 2.0f * EPS_ * v;
    }
    for (int off = 32; off; off >>= 1) acc += __shfl_down(acc, off, 64);
    __shared__ float s[4];
    if ((t & 63) == 0) s[t >> 6] = acc;
    __syncthreads();
    if (t == 0) rowTerm[b] = s[0] + s[1] + s[2] + s[3];
}

__global__ void col_stats(const float* __restrict__ w, float* __restrict__ colTerm) {
    int m = blockIdx.x * 256 + threadIdx.x;
    int d0 = blockIdx.y * 64;
    const float* p = w + (size_t)d0 * M_ + m;
    float acc = 0.f;
    #pragma unroll 8
    for (int d = 0; d < 64; ++d) {
        float v = p[(size_t)d * M_];
        acc += v * v - 2.0f * EPS_ * v;
    }
    atomicAdd(&colTerm[m], acc);
}

__global__ __launch_bounds__(256, 2) void som_gemm(
    const float* __restrict__ A, const float* __restrict__ Wt,
    const float* __restrict__ rowTerm, const float* __restrict__ colTerm,
    unsigned long long* __restrict__ keys)
{
    __shared__ float As[8][128];
    __shared__ float Bs[8][128];
    const int t  = threadIdx.x;
    const int rb = blockIdx.y * 128;
    const int cb = blockIdx.x * 128;
    const int tx = t & 15;
    const int ty = t >> 4;
    float acc[8][8];
    #pragma unroll
    for (int i = 0; i < 8; ++i)
        #pragma unroll
        for (int j = 0; j < 8; ++j) acc[i][j] = 0.f;
    const int la_row = t >> 1, la_k = (t & 1) * 4;
    const int lb_k = t >> 5, lb_n = (t & 31) * 4;
    const float* Aptr = A + (size_t)(rb + la_row) * D_ + la_k;
    const float* Bptr = Wt + (size_t)lb_k * M_ + cb + lb_n;
    for (int k0 = 0; k0 < D_; k0 += 8) {
        float4 av = *(const float4*)(Aptr + k0);
        float4 bv = *(const float4*)(Bptr + (size_t)k0 * M_);
        __syncthreads();
        As[la_k + 0][la_row] = av.x;
        As[la_k + 1][la_row] = av.y;
        As[la_k + 2][la_row] = av.z;
        As[la_k + 3][la_row] = av.w;
        *(float4*)&Bs[lb_k][lb_n] = bv;
        __syncthreads();
        #pragma unroll
        for (int k = 0; k < 8; ++k) {
            float a[8], b[8];
            #pragma unroll
            for (int i = 0; i < 8; ++i) a[i] = As[k][ty * 8 + i];
            #pragma unroll
            for (int j = 0; j < 8; ++j) b[j] = Bs[k][tx * 8 + j];
            #pragma unroll
            for (int i = 0; i < 8; ++i)
                #pragma unroll
                for (int j = 0; j < 8; ++j) acc[i][j] += a[i] * b[j];
        }
    }
    float rT[8], cT[8];
    #pragma unroll
    for (int i = 0; i < 8; ++i) rT[i] = rowTerm[rb + ty * 8 + i];
    #pragma unroll
    for (int j = 0; j < 8; ++j) cT[j] = colTerm[cb + tx * 8 + j];
    const float de2 = (float)D_ * EPS_ * EPS_;
    #pragma unroll
    for (int i = 0; i < 8; ++i) {
        unsigned long long best = ~0ull;
        #pragma unroll
        for (int j = 0; j < 8; ++j) {
            float sq = rT[i] + cT[j] - 2.0f * acc[i][j] + de2;
            sq = fmaxf(sq, 0.0f);
            float dist = sqrtf(sq);
            unsigned long long key =
                ((unsigned long long)__float_as_uint(dist) << 32) |
                (unsigned int)(cb + tx * 8 + j);
            best = umin64(best, key);
        }
        #pragma unroll
        for (int msk = 1; msk <= 8; msk <<= 1) {
            unsigned long long o = __shfl_xor((long long)best, msk, 64);
            best = umin64(best, (unsigned long long)o);
        }
        if (tx == 0) atomicMin(&keys[rb + ty * 8 + i], best);
    }
}

// ---------- finalize: 8 blocks of 256 rows ----------
__global__ void finalize(const unsigned long long* __restrict__ keys,
                         const float* __restrict__ loc,
                         float* __restrict__ out)
{
    int t = threadIdx.x;
    int r = blockIdx.x * 256 + t;
    unsigned long long k = keys[r];
    unsigned int idx = (unsigned int)(k & 0xFFFFFFFFu);
    float dist = __uint_as_float((unsigned int)(k >> 32));
    out[r] = (float)idx;
    out[B_ + 2 * r]     = loc[2 * idx];
    out[B_ + 2 * r + 1] = loc[2 * idx + 1];
    float sum = dist;
    for (int off = 32; off; off >>= 1) sum += __shfl_down(sum, off, 64);
    __shared__ float s[4];
    if ((t & 63) == 0) s[t >> 6] = sum;
    __syncthreads();
    if (t == 0) atomicAdd(&out[3 * B_], (s[0] + s[1] + s[2] + s[3]) / (float)B_);
}

extern "C" void kernel_launch(void* const* d_in, const int* in_sizes, int n_in,
                              void* d_out, int out_size, void* d_ws, size_t ws_size,
                              hipStream_t stream)
{
    const float* x   = (const float*)d_in[0];
    const float* w   = (const float*)d_in[1];
    const float* loc = (const float*)d_in[2];
    float* out = (float*)d_out;

    char* ws = (char*)d_ws;
    unsigned long long* keys = (unsigned long long*)ws;   // 16 KB
    float* rowTerm = (float*)(ws + (16 << 10));           //  8 KB
    float* colTerm = (float*)(ws + (24 << 10));           // 64 KB
    _Float16* xh  = (_Float16*)(ws + (1ull << 20));       //  4 MB
    _Float16* xl  = (_Float16*)(ws + (5ull << 20));       //  4 MB
    _Float16* wth = (_Float16*)(ws + (9ull << 20));       // 32 MB
    _Float16* wtl = (_Float16*)(ws + (41ull << 20));      // 32 MB
    const size_t NEED = 73ull << 20;

    hipMemsetAsync(keys, 0xFF, B_ * sizeof(unsigned long long), stream);
    hipMemsetAsync(colTerm, 0, M_ * sizeof(float), stream);
    hipMemsetAsync(out + 3 * B_, 0, sizeof(float), stream);

    if (ws_size >= NEED) {
        xconv<<<B_, 256, 0, stream>>>(x, xh, xl, rowTerm);
        wconv<<<dim3(M_ / 64, D_ / 64), 256, 0, stream>>>(w, wth, wtl, colTerm);
        som_mfma<<<dim3(M_ / 128, B_ / 128), 256, 0, stream>>>(
            xh, xl, wth, wtl, rowTerm, colTerm, keys);
    } else {
        row_stats<<<B_, 256, 0, stream>>>(x, rowTerm);
        col_stats<<<dim3(M_ / 256, D_ / 64), 256, 0, stream>>>(w, colTerm);
        som_gemm<<<dim3(M_ / 128, B_ / 128), 256, 0, stream>>>(
            x, w, rowTerm, colTerm, keys);
    }
    finalize<<<8, 256, 0, stream>>>(keys, loc, out);
}

// Round 6
// 354.772 us; speedup vs baseline: 1.1618x; 1.1334x over previous
//
#include <hip/hip_runtime.h>
#include <cstdint>
#include <cstddef>

// SOM BMU: dists[b,m] = ||x[b] - W[:,m] + eps||, argmin/min over m.
//   sq = rowTerm[b] + colTerm[m] - 2*dot(x[b],W[:,m]) + D*eps^2
// dot via split-precision f16 MFMA (xh.wh + xh.wl + xl.wh, ~2^-22 rel err).
// R6: VGPR-staged prefetch pipeline (global loads issued a full compute
// phase before their ds_write) + XOR-swizzled fragment-major LDS:
//   chunk g (row=g>>2, ch=g&3) -> slot sigma(g) = fm ^ ((fm>>3)&7),
//   fm = (g>>6)*64 + (g&3)*16 + ((g>>2)&15)
// Coalesced global (wave = contiguous 1KB), conflict-free ds_write and
// ds_read (every aligned 8-lane group covers all 8 bank quads).
// Argmin via packed u64 key (dist_bits<<32 | m) + atomicMin.

#define B_  2048
#define D_  1024
#define M_  16384
#define EPS_ 1e-6f

typedef _Float16 v8h __attribute__((ext_vector_type(8)));
typedef _Float16 v4h __attribute__((ext_vector_type(4)));
typedef float    v4f __attribute__((ext_vector_type(4)));

static __device__ __forceinline__ unsigned long long umin64(unsigned long long a,
                                                            unsigned long long b) {
    return a < b ? a : b;
}

// ---------- convert x -> xh,xl (f16) + rowTerm ----------
__global__ void xconv(const float* __restrict__ x,
                      _Float16* __restrict__ xh, _Float16* __restrict__ xl,
                      float* __restrict__ rowTerm) {
    int b = blockIdx.x;
    int t = threadIdx.x;  // 256
    const float4 v = *(const float4*)(x + (size_t)b * D_ + t * 4);
    v4h h, l;
    float acc = 0.f;
    float vv[4] = {v.x, v.y, v.z, v.w};
    #pragma unroll
    for (int e = 0; e < 4; ++e) {
        _Float16 hi = (_Float16)vv[e];
        float lo = vv[e] - (float)hi;
        h[e] = hi; l[e] = (_Float16)lo;
        acc += vv[e] * vv[e] + 2.0f * EPS_ * vv[e];
    }
    *(v4h*)(xh + (size_t)b * D_ + t * 4) = h;
    *(v4h*)(xl + (size_t)b * D_ + t * 4) = l;
    for (int off = 32; off; off >>= 1) acc += __shfl_down(acc, off, 64);
    __shared__ float s[4];
    if ((t & 63) == 0) s[t >> 6] = acc;
    __syncthreads();
    if (t == 0) rowTerm[b] = s[0] + s[1] + s[2] + s[3];
}

// ---------- convert+transpose W -> Wth,Wtl [m][d] + colTerm ----------
__global__ void wconv(const float* __restrict__ W,
                      _Float16* __restrict__ wth, _Float16* __restrict__ wtl,
                      float* __restrict__ colTerm) {
    __shared__ float tile[64][65];
    const int t = threadIdx.x;
    const int m0 = blockIdx.x * 64;
    const int d0 = blockIdx.y * 64;
    const int dloc = t >> 4, mq = (t & 15) * 4;
    #pragma unroll
    for (int s = 0; s < 4; ++s) {
        float4 v = *(const float4*)(W + (size_t)(d0 + dloc + 16 * s) * M_ + m0 + mq);
        tile[dloc + 16 * s][mq + 0] = v.x;
        tile[dloc + 16 * s][mq + 1] = v.y;
        tile[dloc + 16 * s][mq + 2] = v.z;
        tile[dloc + 16 * s][mq + 3] = v.w;
    }
    __syncthreads();
    const int mloc = t >> 2;
    const int dc = (t & 3) * 16;
    v8h h0, l0, h1, l1;
    float acc = 0.f;
    #pragma unroll
    for (int e = 0; e < 8; ++e) {
        float v = tile[dc + e][mloc];
        _Float16 hi = (_Float16)v;
        h0[e] = hi; l0[e] = (_Float16)(v - (float)hi);
        acc += v * v - 2.0f * EPS_ * v;
    }
    #pragma unroll
    for (int e = 0; e < 8; ++e) {
        float v = tile[dc + 8 + e][mloc];
        _Float16 hi = (_Float16)v;
        h1[e] = hi; l1[e] = (_Float16)(v - (float)hi);
        acc += v * v - 2.0f * EPS_ * v;
    }
    _Float16* oh = wth + (size_t)(m0 + mloc) * D_ + d0 + dc;
    _Float16* ol = wtl + (size_t)(m0 + mloc) * D_ + d0 + dc;
    *(v8h*)oh = h0; *(v8h*)(oh + 8) = h1;
    *(v8h*)ol = l0; *(v8h*)(ol + 8) = l1;
    acc += __shfl_xor(acc, 1, 64);
    acc += __shfl_xor(acc, 2, 64);
    if ((t & 3) == 0) atomicAdd(&colTerm[m0 + mloc], acc);
}

// ---------- main MFMA distance GEMM + argmin ----------
// 128x128 tile, 4 waves (2x2 of 64x64), BK=32, 16x16x32 f16 MFMA.
__global__ __launch_bounds__(256, 2) void som_mfma(
    const _Float16* __restrict__ xh, const _Float16* __restrict__ xl,
    const _Float16* __restrict__ wth, const _Float16* __restrict__ wtl,
    const float* __restrict__ rowTerm, const float* __restrict__ colTerm,
    unsigned long long* __restrict__ keys)
{
    __shared__ __align__(16) _Float16 smem[16384];  // 32 KB: Ah|Al|Bh|Bl
    _Float16* Ah = smem;
    _Float16* Al = smem + 4096;
    _Float16* Bh = smem + 8192;
    _Float16* Bl = smem + 12288;

    const int t  = threadIdx.x;
    const int rb = blockIdx.y * 128;
    const int cb = blockIdx.x * 128;
    const int L  = t & 63, w = t >> 6;
    const int wro = (w >> 1) * 64, wco = (w & 1) * 64;
    const int c16 = L & 15, kq = L >> 4;

    // global source chunks: g=t (rows 0..63) and g=t+256 (rows 64..127);
    // wave reads a contiguous 1 KB run per call -> fully coalesced.
    const size_t ga0 = (size_t)(rb + (t >> 2)) * 2048 + (t & 3) * 16;
    const size_t ga1 = ga0 + 64ull * 2048;
    const size_t gb0 = (size_t)(cb + (t >> 2)) * 2048 + (t & 3) * 16;
    const size_t gb1 = gb0 + 64ull * 2048;

    // LDS dest byte offsets: sigma(t) and sigma(t+256) = sigma(t)+256
    int fm = ((t >> 6) << 6) + ((t & 3) << 4) + ((t >> 2) & 15);
    const int ws0 = (fm ^ ((fm >> 3) & 7)) * 16;
    const int ws1 = ws0 + 4096;

    const char* pxh = (const char*)xh;
    const char* pxl = (const char*)xl;
    const char* pwh = (const char*)wth;
    const char* pwl = (const char*)wtl;

    v4f acc[4][4];
    #pragma unroll
    for (int i = 0; i < 4; ++i)
        #pragma unroll
        for (int j = 0; j < 4; ++j) acc[i][j] = (v4f){0.f, 0.f, 0.f, 0.f};

    // fragment read offsets (f16 units): slot = rg*64 + Lswz
    const int Lswz = (L & 56) + ((L & 7) ^ ((L >> 3) & 7));
    int ia[4], ib[4];
    #pragma unroll
    for (int i = 0; i < 4; ++i) {
        ia[i] = (((wro >> 4) + i) * 64 + Lswz) * 8;
        ib[i] = (((wco >> 4) + i) * 64 + Lswz) * 8;
    }

    // prologue: load + stage tile 0
    float4 rA0h = *(const float4*)(pxh + ga0);
    float4 rA1h = *(const float4*)(pxh + ga1);
    float4 rA0l = *(const float4*)(pxl + ga0);
    float4 rA1l = *(const float4*)(pxl + ga1);
    float4 rB0h = *(const float4*)(pwh + gb0);
    float4 rB1h = *(const float4*)(pwh + gb1);
    float4 rB0l = *(const float4*)(pwl + gb0);
    float4 rB1l = *(const float4*)(pwl + gb1);
    *(float4*)((char*)Ah + ws0) = rA0h;  *(float4*)((char*)Ah + ws1) = rA1h;
    *(float4*)((char*)Al + ws0) = rA0l;  *(float4*)((char*)Al + ws1) = rA1l;
    *(float4*)((char*)Bh + ws0) = rB0h;  *(float4*)((char*)Bh + ws1) = rB1h;
    *(float4*)((char*)Bl + ws0) = rB0l;  *(float4*)((char*)Bl + ws1) = rB1l;
    __syncthreads();

    for (int kb = 64; kb <= 2048; kb += 64) {
        const bool more = (kb < 2048);
        if (more) {   // prefetch tile kb into VGPRs; consumed after the barrier
            rA0h = *(const float4*)(pxh + ga0 + kb);
            rA1h = *(const float4*)(pxh + ga1 + kb);
            rA0l = *(const float4*)(pxl + ga0 + kb);
            rA1l = *(const float4*)(pxl + ga1 + kb);
            rB0h = *(const float4*)(pwh + gb0 + kb);
            rB1h = *(const float4*)(pwh + gb1 + kb);
            rB0l = *(const float4*)(pwl + gb0 + kb);
            rB1l = *(const float4*)(pwl + gb1 + kb);
        }

        v8h ah[4], al4[4], bh4[4], bl4[4];
        #pragma unroll
        for (int i = 0; i < 4; ++i) {
            ah[i]  = *(const v8h*)(Ah + ia[i]);
            al4[i] = *(const v8h*)(Al + ia[i]);
            bh4[i] = *(const v8h*)(Bh + ib[i]);
            bl4[i] = *(const v8h*)(Bl + ib[i]);
        }
        #pragma unroll
        for (int i = 0; i < 4; ++i)
            #pragma unroll
            for (int j = 0; j < 4; ++j) {
                acc[i][j] = __builtin_amdgcn_mfma_f32_16x16x32_f16(ah[i],  bh4[j], acc[i][j], 0, 0, 0);
                acc[i][j] = __builtin_amdgcn_mfma_f32_16x16x32_f16(ah[i],  bl4[j], acc[i][j], 0, 0, 0);
                acc[i][j] = __builtin_amdgcn_mfma_f32_16x16x32_f16(al4[i], bh4[j], acc[i][j], 0, 0, 0);
            }

        __syncthreads();   // all fragment reads of this tile done
        if (more) {
            *(float4*)((char*)Ah + ws0) = rA0h;  *(float4*)((char*)Ah + ws1) = rA1h;
            *(float4*)((char*)Al + ws0) = rA0l;  *(float4*)((char*)Al + ws1) = rA1l;
            *(float4*)((char*)Bh + ws0) = rB0h;  *(float4*)((char*)Bh + ws1) = rB1h;
            *(float4*)((char*)Bl + ws0) = rB0l;  *(float4*)((char*)Bl + ws1) = rB1l;
        }
        __syncthreads();   // staging visible to all
    }

    // epilogue: C/D layout col=lane&15, row=(lane>>4)*4+reg  [verified m89/m91]
    float cT[4];
    #pragma unroll
    for (int j = 0; j < 4; ++j) cT[j] = colTerm[cb + wco + j * 16 + c16];
    const float de2 = (float)D_ * EPS_ * EPS_;
    #pragma unroll
    for (int i = 0; i < 4; ++i) {
        #pragma unroll
        for (int r = 0; r < 4; ++r) {
            int row_g = rb + wro + i * 16 + kq * 4 + r;
            float rt = rowTerm[row_g];
            unsigned long long best = ~0ull;
            #pragma unroll
            for (int j = 0; j < 4; ++j) {
                float sq = rt + cT[j] - 2.0f * acc[i][j][r] + de2;
                sq = fmaxf(sq, 0.0f);
                float dist = sqrtf(sq);
                unsigned long long key =
                    ((unsigned long long)__float_as_uint(dist) << 32) |
                    (unsigned int)(cb + wco + j * 16 + c16);
                best = umin64(best, key);
            }
            #pragma unroll
            for (int m = 1; m <= 8; m <<= 1) {
                unsigned long long o =
                    (unsigned long long)__shfl_xor((long long)best, m, 64);
                best = umin64(best, o);
            }
            if (c16 == 0) atomicMin(&keys[row_g], best);
        }
    }
}

// ---------- fallback fp32 path (used only if ws too small) ----------
__global__ void row_stats(const float* __restrict__ x, float* __restrict__ rowTerm) {
    int b = blockIdx.x;
    const float* xr = x + (size_t)b * D_;
    int t = threadIdx.x;
    float acc = 0.f;
    for (int i = t; i < D_; i += 256) {
        float v = xr[i];
        acc += v * v + 2.0f * EPS_ * v;
    }
    for (int off = 32; off; off >>= 1) acc += __shfl_down(acc, off, 64);
    __shared__ float s[4];
    if ((t & 63) == 0) s[t >> 6] = acc;
    __syncthreads();
    if (t == 0) rowTerm[b] = s[0] + s[1] + s[2] + s[3];
}

__global__ void col_stats(const float* __restrict__ w, float* __restrict__ colTerm) {
    int m = blockIdx.x * 256 + threadIdx.x;
    int d0 = blockIdx.y * 64;
    const float* p = w + (size_t)d0 * M_ + m;
    float acc = 0.f;
    #pragma unroll 8
    for (int d = 0; d < 64; ++d) {
        float v = p[(size_t)d * M_];
        acc += v * v - 2.0f * EPS_ * v;
    }
    atomicAdd(&colTerm[m], acc);
}

__global__ __launch_bounds__(256, 2) void som_gemm(
    const float* __restrict__ A, const float* __restrict__ Wt,
    const float* __restrict__ rowTerm, const float* __restrict__ colTerm,
    unsigned long long* __restrict__ keys)
{
    __shared__ float As[8][128];
    __shared__ float Bs[8][128];
    const int t  = threadIdx.x;
    const int rb = blockIdx.y * 128;
    const int cb = blockIdx.x * 128;
    const int tx = t & 15;
    const int ty = t >> 4;
    float acc[8][8];
    #pragma unroll
    for (int i = 0; i < 8; ++i)
        #pragma unroll
        for (int j = 0; j < 8; ++j) acc[i][j] = 0.f;
    const int la_row = t >> 1, la_k = (t & 1) * 4;
    const int lb_k = t >> 5, lb_n = (t & 31) * 4;
    const float* Aptr = A + (size_t)(rb + la_row) * D_ + la_k;
    const float* Bptr = Wt + (size_t)lb_k * M_ + cb + lb_n;
    for (int k0 = 0; k0 < D_; k0 += 8) {
        float4 av = *(const float4*)(Aptr + k0);
        float4 bv = *(const float4*)(Bptr + (size_t)k0 * M_);
        __syncthreads();
        As[la_k + 0][la_row] = av.x;
        As[la_k + 1][la_row] = av.y;
        As[la_k + 2][la_row] = av.z;
        As[la_k + 3][la_row] = av.w;
        *(float4*)&Bs[lb_k][lb_n] = bv;
        __syncthreads();
        #pragma unroll
        for (int k = 0; k < 8; ++k) {
            float a[8], b[8];
            #pragma unroll
            for (int i = 0; i < 8; ++i) a[i] = As[k][ty * 8 + i];
            #pragma unroll
            for (int j = 0; j < 8; ++j) b[j] = Bs[k][tx * 8 + j];
            #pragma unroll
            for (int i = 0; i < 8; ++i)
                #pragma unroll
                for (int j = 0; j < 8; ++j) acc[i][j] += a[i] * b[j];
        }
    }
    float rT[8], cT[8];
    #pragma unroll
    for (int i = 0; i < 8; ++i) rT[i] = rowTerm[rb + ty * 8 + i];
    #pragma unroll
    for (int j = 0; j < 8; ++j) cT[j] = colTerm[cb + tx * 8 + j];
    const float de2 = (float)D_ * EPS_ * EPS_;
    #pragma unroll
    for (int i = 0; i < 8; ++i) {
        unsigned long long best = ~0ull;
        #pragma unroll
        for (int j = 0; j < 8; ++j) {
            float sq = rT[i] + cT[j] - 2.0f * acc[i][j] + de2;
            sq = fmaxf(sq, 0.0f);
            float dist = sqrtf(sq);
            unsigned long long key =
                ((unsigned long long)__float_as_uint(dist) << 32) |
                (unsigned int)(cb + tx * 8 + j);
            best = umin64(best, key);
        }
        #pragma unroll
        for (int msk = 1; msk <= 8; msk <<= 1) {
            unsigned long long o = __shfl_xor((long long)best, msk, 64);
            best = umin64(best, (unsigned long long)o);
        }
        if (tx == 0) atomicMin(&keys[rb + ty * 8 + i], best);
    }
}

// ---------- finalize: 8 blocks of 256 rows ----------
__global__ void finalize(const unsigned long long* __restrict__ keys,
                         const float* __restrict__ loc,
                         float* __restrict__ out)
{
    int t = threadIdx.x;
    int r = blockIdx.x * 256 + t;
    unsigned long long k = keys[r];
    unsigned int idx = (unsigned int)(k & 0xFFFFFFFFu);
    float dist = __uint_as_float((unsigned int)(k >> 32));
    out[r] = (float)idx;
    out[B_ + 2 * r]     = loc[2 * idx];
    out[B_ + 2 * r + 1] = loc[2 * idx + 1];
    float sum = dist;
    for (int off = 32; off; off >>= 1) sum += __shfl_down(sum, off, 64);
    __shared__ float s[4];
    if ((t & 63) == 0) s[t >> 6] = sum;
    __syncthreads();
    if (t == 0) atomicAdd(&out[3 * B_], (s[0] + s[1] + s[2] + s[3]) / (float)B_);
}

extern "C" void kernel_launch(void* const* d_in, const int* in_sizes, int n_in,
                              void* d_out, int out_size, void* d_ws, size_t ws_size,
                              hipStream_t stream)
{
    const float* x   = (const float*)d_in[0];
    const float* w   = (const float*)d_in[1];
    const float* loc = (const float*)d_in[2];
    float* out = (float*)d_out;

    char* ws = (char*)d_ws;
    unsigned long long* keys = (unsigned long long*)ws;   // 16 KB
    float* rowTerm = (float*)(ws + (16 << 10));           //  8 KB
    float* colTerm = (float*)(ws + (24 << 10));           // 64 KB
    _Float16* xh  = (_Float16*)(ws + (1ull << 20));       //  4 MB
    _Float16* xl  = (_Float16*)(ws + (5ull << 20));       //  4 MB
    _Float16* wth = (_Float16*)(ws + (9ull << 20));       // 32 MB
    _Float16* wtl = (_Float16*)(ws + (41ull << 20));      // 32 MB
    const size_t NEED = 73ull << 20;

    hipMemsetAsync(keys, 0xFF, B_ * sizeof(unsigned long long), stream);
    hipMemsetAsync(colTerm, 0, M_ * sizeof(float), stream);
    hipMemsetAsync(out + 3 * B_, 0, sizeof(float), stream);

    if (ws_size >= NEED) {
        xconv<<<B_, 256, 0, stream>>>(x, xh, xl, rowTerm);
        wconv<<<dim3(M_ / 64, D_ / 64), 256, 0, stream>>>(w, wth, wtl, colTerm);
        som_mfma<<<dim3(M_ / 128, B_ / 128), 256, 0, stream>>>(
            xh, xl, wth, wtl, rowTerm, colTerm, keys);
    } else {
        row_stats<<<B_, 256, 0, stream>>>(x, rowTerm);
        col_stats<<<dim3(M_ / 256, D_ / 64), 256, 0, stream>>>(w, colTerm);
        som_gemm<<<dim3(M_ / 128, B_ / 128), 256, 0, stream>>>(
            x, w, rowTerm, colTerm, keys);
    }
    finalize<<<8, 256, 0, stream>>>(keys, loc, out);
}

// Round 7
// 344.326 us; speedup vs baseline: 1.1971x; 1.0303x over previous
//
#include <hip/hip_runtime.h>
#include <cstdint>
#include <cstddef>

// SOM BMU: dists[b,m] = ||x[b] - W[:,m] + eps||, argmin/min over m.
//   sq = rowTerm[b] + colTerm[m] - 2*dot(x[b],W[:,m]) + D*eps^2
// dot via split-precision f16 MFMA (xh.wh + xh.wl + xl.wh, ~2^-22 rel err).
// R7: double-buffered LDS (2x32KB), ONE barrier per K-step:
//   iter k: ds_write buf[1-p] (tile k+1, regs prefetched a full iter ago),
//           issue global loads tile k+2, ds_read+MFMA buf[p], barrier.
// XOR-swizzled fragment-major LDS (R6-verified, 0 bank conflicts):
//   chunk g -> slot fm ^ ((fm>>3)&7), fm=(g>>6)*64+(g&3)*16+((g>>2)&15).
// XCD-aware block swizzle: resident blocks per XCD share ~2 col-tiles of W.
// Argmin via packed u64 key (dist_bits<<32 | m) + atomicMin.

#define B_  2048
#define D_  1024
#define M_  16384
#define EPS_ 1e-6f

typedef _Float16 v8h __attribute__((ext_vector_type(8)));
typedef _Float16 v4h __attribute__((ext_vector_type(4)));
typedef float    v4f __attribute__((ext_vector_type(4)));

static __device__ __forceinline__ unsigned long long umin64(unsigned long long a,
                                                            unsigned long long b) {
    return a < b ? a : b;
}

// ---------- convert x -> xh,xl (f16) + rowTerm ----------
__global__ void xconv(const float* __restrict__ x,
                      _Float16* __restrict__ xh, _Float16* __restrict__ xl,
                      float* __restrict__ rowTerm) {
    int b = blockIdx.x;
    int t = threadIdx.x;  // 256
    const float4 v = *(const float4*)(x + (size_t)b * D_ + t * 4);
    v4h h, l;
    float acc = 0.f;
    float vv[4] = {v.x, v.y, v.z, v.w};
    #pragma unroll
    for (int e = 0; e < 4; ++e) {
        _Float16 hi = (_Float16)vv[e];
        float lo = vv[e] - (float)hi;
        h[e] = hi; l[e] = (_Float16)lo;
        acc += vv[e] * vv[e] + 2.0f * EPS_ * vv[e];
    }
    *(v4h*)(xh + (size_t)b * D_ + t * 4) = h;
    *(v4h*)(xl + (size_t)b * D_ + t * 4) = l;
    for (int off = 32; off; off >>= 1) acc += __shfl_down(acc, off, 64);
    __shared__ float s[4];
    if ((t & 63) == 0) s[t >> 6] = acc;
    __syncthreads();
    if (t == 0) rowTerm[b] = s[0] + s[1] + s[2] + s[3];
}

// ---------- convert+transpose W -> Wth,Wtl [m][d] + colTerm ----------
__global__ void wconv(const float* __restrict__ W,
                      _Float16* __restrict__ wth, _Float16* __restrict__ wtl,
                      float* __restrict__ colTerm) {
    __shared__ float tile[64][65];
    const int t = threadIdx.x;
    const int m0 = blockIdx.x * 64;
    const int d0 = blockIdx.y * 64;
    const int dloc = t >> 4, mq = (t & 15) * 4;
    #pragma unroll
    for (int s = 0; s < 4; ++s) {
        float4 v = *(const float4*)(W + (size_t)(d0 + dloc + 16 * s) * M_ + m0 + mq);
        tile[dloc + 16 * s][mq + 0] = v.x;
        tile[dloc + 16 * s][mq + 1] = v.y;
        tile[dloc + 16 * s][mq + 2] = v.z;
        tile[dloc + 16 * s][mq + 3] = v.w;
    }
    __syncthreads();
    const int mloc = t >> 2;
    const int dc = (t & 3) * 16;
    v8h h0, l0, h1, l1;
    float acc = 0.f;
    #pragma unroll
    for (int e = 0; e < 8; ++e) {
        float v = tile[dc + e][mloc];
        _Float16 hi = (_Float16)v;
        h0[e] = hi; l0[e] = (_Float16)(v - (float)hi);
        acc += v * v - 2.0f * EPS_ * v;
    }
    #pragma unroll
    for (int e = 0; e < 8; ++e) {
        float v = tile[dc + 8 + e][mloc];
        _Float16 hi = (_Float16)v;
        h1[e] = hi; l1[e] = (_Float16)(v - (float)hi);
        acc += v * v - 2.0f * EPS_ * v;
    }
    _Float16* oh = wth + (size_t)(m0 + mloc) * D_ + d0 + dc;
    _Float16* ol = wtl + (size_t)(m0 + mloc) * D_ + d0 + dc;
    *(v8h*)oh = h0; *(v8h*)(oh + 8) = h1;
    *(v8h*)ol = l0; *(v8h*)(ol + 8) = l1;
    acc += __shfl_xor(acc, 1, 64);
    acc += __shfl_xor(acc, 2, 64);
    if ((t & 3) == 0) atomicAdd(&colTerm[m0 + mloc], acc);
}

// ---------- main MFMA distance GEMM + argmin ----------
// 128x128 tile, 4 waves (2x2 of 64x64), BK=32, 16x16x32 f16 MFMA.
__global__ __launch_bounds__(256, 2) void som_mfma(
    const _Float16* __restrict__ xh, const _Float16* __restrict__ xl,
    const _Float16* __restrict__ wth, const _Float16* __restrict__ wtl,
    const float* __restrict__ rowTerm, const float* __restrict__ colTerm,
    unsigned long long* __restrict__ keys)
{
    __shared__ __align__(16) _Float16 smem[32768];  // 64 KB: 2 buffers
    // buffer p at smem + p*16384: Ah|Al|Bh|Bl each 4096 f16

    const int t  = threadIdx.x;
    // XCD-aware swizzle: 8 groups of 256 blocks; within a group 16 ctiles
    // x 16 rtiles -> each XCD's resident blocks share ~2 ctiles of W.
    const int g   = blockIdx.x;
    const int grp = g >> 8, loc = g & 255;
    const int cb  = ((grp << 4) + (loc & 15)) * 128;
    const int rb  = (loc >> 4) * 128;

    const int L  = t & 63, w = t >> 6;
    const int wro = (w >> 1) * 64, wco = (w & 1) * 64;
    const int c16 = L & 15, kq = L >> 4;

    // global source chunks: g0=t (rows 0..63), g1=t+256 (rows 64..127)
    const size_t ga0 = (size_t)(rb + (t >> 2)) * 2048 + (t & 3) * 16;
    const size_t ga1 = ga0 + 64ull * 2048;
    const size_t gb0 = (size_t)(cb + (t >> 2)) * 2048 + (t & 3) * 16;
    const size_t gb1 = gb0 + 64ull * 2048;

    // LDS dest byte offsets within a buffer (R6-verified swizzle)
    int fm = ((t >> 6) << 6) + ((t & 3) << 4) + ((t >> 2) & 15);
    const int ws0 = (fm ^ ((fm >> 3) & 7)) * 16;
    const int ws1 = ws0 + 4096;

    const char* pxh = (const char*)xh;
    const char* pxl = (const char*)xl;
    const char* pwh = (const char*)wth;
    const char* pwl = (const char*)wtl;

    v4f acc[4][4];
    #pragma unroll
    for (int i = 0; i < 4; ++i)
        #pragma unroll
        for (int j = 0; j < 4; ++j) acc[i][j] = (v4f){0.f, 0.f, 0.f, 0.f};

    // fragment read offsets (f16 units): slot = rg*64 + Lswz
    const int Lswz = (L & 56) + ((L & 7) ^ ((L >> 3) & 7));
    int ia[4], ib[4];
    #pragma unroll
    for (int i = 0; i < 4; ++i) {
        ia[i] = (((wro >> 4) + i) * 64 + Lswz) * 8;
        ib[i] = (((wco >> 4) + i) * 64 + Lswz) * 8;
    }

    float4 rA0h, rA1h, rA0l, rA1l, rB0h, rB1h, rB0l, rB1l;

    #define LOAD_REGS(kb)                                                       \
        do {                                                                    \
            rA0h = *(const float4*)(pxh + ga0 + (kb));                          \
            rA1h = *(const float4*)(pxh + ga1 + (kb));                          \
            rA0l = *(const float4*)(pxl + ga0 + (kb));                          \
            rA1l = *(const float4*)(pxl + ga1 + (kb));                          \
            rB0h = *(const float4*)(pwh + gb0 + (kb));                          \
            rB1h = *(const float4*)(pwh + gb1 + (kb));                          \
            rB0l = *(const float4*)(pwl + gb0 + (kb));                          \
            rB1l = *(const float4*)(pwl + gb1 + (kb));                          \
        } while (0)

    #define WRITE_LDS(base)                                                     \
        do {                                                                    \
            char* Ahb = (char*)(base);                                          \
            *(float4*)(Ahb + ws0)          = rA0h;                              \
            *(float4*)(Ahb + ws1)          = rA1h;                              \
            *(float4*)(Ahb + 8192 + ws0)   = rA0l;                              \
            *(float4*)(Ahb + 8192 + ws1)   = rA1l;                              \
            *(float4*)(Ahb + 16384 + ws0)  = rB0h;                              \
            *(float4*)(Ahb + 16384 + ws1)  = rB1h;                              \
            *(float4*)(Ahb + 24576 + ws0)  = rB0l;                              \
            *(float4*)(Ahb + 24576 + ws1)  = rB1l;                              \
        } while (0)

    #define COMPUTE(base)                                                       \
        do {                                                                    \
            const _Float16* Ahp = (base);                                       \
            const _Float16* Alp = (base) + 4096;                                \
            const _Float16* Bhp = (base) + 8192;                                \
            const _Float16* Blp = (base) + 12288;                               \
            v8h ah[4], al4[4], bh4[4], bl4[4];                                  \
            _Pragma("unroll")                                                   \
            for (int i = 0; i < 4; ++i) {                                       \
                ah[i]  = *(const v8h*)(Ahp + ia[i]);                            \
                al4[i] = *(const v8h*)(Alp + ia[i]);                            \
                bh4[i] = *(const v8h*)(Bhp + ib[i]);                            \
                bl4[i] = *(const v8h*)(Blp + ib[i]);                            \
            }                                                                   \
            _Pragma("unroll")                                                   \
            for (int i = 0; i < 4; ++i)                                         \
                _Pragma("unroll")                                               \
                for (int j = 0; j < 4; ++j) {                                   \
                    acc[i][j] = __builtin_amdgcn_mfma_f32_16x16x32_f16(         \
                        ah[i],  bh4[j], acc[i][j], 0, 0, 0);                    \
                    acc[i][j] = __builtin_amdgcn_mfma_f32_16x16x32_f16(         \
                        ah[i],  bl4[j], acc[i][j], 0, 0, 0);                    \
                    acc[i][j] = __builtin_amdgcn_mfma_f32_16x16x32_f16(         \
                        al4[i], bh4[j], acc[i][j], 0, 0, 0);                    \
                }                                                               \
        } while (0)

    _Float16* buf0 = smem;
    _Float16* buf1 = smem + 16384;

    // prologue: stage tile 0, start tile 1
    LOAD_REGS(0);
    WRITE_LDS(buf0);
    LOAD_REGS(64);
    __syncthreads();

    // 32 K-steps, unrolled x2; tiles 32/33 are garbage writes/loads that
    // are never read (workspace padded so over-reads stay in-bounds).
    for (int kb = 0; kb < 2048; kb += 128) {
        WRITE_LDS(buf1);            // tile kb/64 + 1 (regs from last iter)
        LOAD_REGS(kb + 128);        // tile kb/64 + 2
        COMPUTE(buf0);              // tile kb/64
        __syncthreads();

        WRITE_LDS(buf0);            // tile kb/64 + 2
        LOAD_REGS(kb + 192);        // tile kb/64 + 3
        COMPUTE(buf1);              // tile kb/64 + 1
        __syncthreads();
    }

    // epilogue: C/D layout col=lane&15, row=(lane>>4)*4+reg  [verified m89/m91]
    float cT[4];
    #pragma unroll
    for (int j = 0; j < 4; ++j) cT[j] = colTerm[cb + wco + j * 16 + c16];
    const float de2 = (float)D_ * EPS_ * EPS_;
    #pragma unroll
    for (int i = 0; i < 4; ++i) {
        #pragma unroll
        for (int r = 0; r < 4; ++r) {
            int row_g = rb + wro + i * 16 + kq * 4 + r;
            float rt = rowTerm[row_g];
            unsigned long long best = ~0ull;
            #pragma unroll
            for (int j = 0; j < 4; ++j) {
                float sq = rt + cT[j] - 2.0f * acc[i][j][r] + de2;
                sq = fmaxf(sq, 0.0f);
                float dist = sqrtf(sq);
                unsigned long long key =
                    ((unsigned long long)__float_as_uint(dist) << 32) |
                    (unsigned int)(cb + wco + j * 16 + c16);
                best = umin64(best, key);
            }
            #pragma unroll
            for (int m = 1; m <= 8; m <<= 1) {
                unsigned long long o =
                    (unsigned long long)__shfl_xor((long long)best, m, 64);
                best = umin64(best, o);
            }
            if (c16 == 0) atomicMin(&keys[row_g], best);
        }
    }
    #undef LOAD_REGS
    #undef WRITE_LDS
    #undef COMPUTE
}

// ---------- fallback fp32 path (used only if ws too small) ----------
__global__ void row_stats(const float* __restrict__ x, float* __restrict__ rowTerm) {
    int b = blockIdx.x;
    const float* xr = x + (size_t)b * D_;
    int t = threadIdx.x;
    float acc = 0.f;
    for (int i = t; i < D_; i += 256) {
        float v = xr[i];
        acc += v * v + 2.0f * EPS_ * v;
    }
    for (int off = 32; off; off >>= 1) acc += __shfl_down(acc, off, 64);
    __shared__ float s[4];
    if ((t & 63) == 0) s[t >> 6] = acc;
    __syncthreads();
    if (t == 0) rowTerm[b] = s[0] + s[1] + s[2] + s[3];
}

__global__ void col_stats(const float* __restrict__ w, float* __restrict__ colTerm) {
    int m = blockIdx.x * 256 + threadIdx.x;
    int d0 = blockIdx.y * 64;
    const float* p = w + (size_t)d0 * M_ + m;
    float acc = 0.f;
    #pragma unroll 8
    for (int d = 0; d < 64; ++d) {
        float v = p[(size_t)d * M_];
        acc += v * v - 2.0f * EPS_ * v;
    }
    atomicAdd(&colTerm[m], acc);
}

__global__ __launch_bounds__(256, 2) void som_gemm(
    const float* __restrict__ A, const float* __restrict__ Wt,
    const float* __restrict__ rowTerm, const float* __restrict__ colTerm,
    unsigned long long* __restrict__ keys)
{
    __shared__ float As[8][128];
    __shared__ float Bs[8][128];
    const int t  = threadIdx.x;
    const int rb = blockIdx.y * 128;
    const int cb = blockIdx.x * 128;
    const int tx = t & 15;
    const int ty = t >> 4;
    float acc[8][8];
    #pragma unroll
    for (int i = 0; i < 8; ++i)
        #pragma unroll
        for (int j = 0; j < 8; ++j) acc[i][j] = 0.f;
    const int la_row = t >> 1, la_k = (t & 1) * 4;
    const int lb_k = t >> 5, lb_n = (t & 31) * 4;
    const float* Aptr = A + (size_t)(rb + la_row) * D_ + la_k;
    const float* Bptr = Wt + (size_t)lb_k * M_ + cb + lb_n;
    for (int k0 = 0; k0 < D_; k0 += 8) {
        float4 av = *(const float4*)(Aptr + k0);
        float4 bv = *(const float4*)(Bptr + (size_t)k0 * M_);
        __syncthreads();
        As[la_k + 0][la_row] = av.x;
        As[la_k + 1][la_row] = av.y;
        As[la_k + 2][la_row] = av.z;
        As[la_k + 3][la_row] = av.w;
        *(float4*)&Bs[lb_k][lb_n] = bv;
        __syncthreads();
        #pragma unroll
        for (int k = 0; k < 8; ++k) {
            float a[8], b[8];
            #pragma unroll
            for (int i = 0; i < 8; ++i) a[i] = As[k][ty * 8 + i];
            #pragma unroll
            for (int j = 0; j < 8; ++j) b[j] = Bs[k][tx * 8 + j];
            #pragma unroll
            for (int i = 0; i < 8; ++i)
                #pragma unroll
                for (int j = 0; j < 8; ++j) acc[i][j] += a[i] * b[j];
        }
    }
    float rT[8], cT[8];
    #pragma unroll
    for (int i = 0; i < 8; ++i) rT[i] = rowTerm[rb + ty * 8 + i];
    #pragma unroll
    for (int j = 0; j < 8; ++j) cT[j] = colTerm[cb + tx * 8 + j];
    const float de2 = (float)D_ * EPS_ * EPS_;
    #pragma unroll
    for (int i = 0; i < 8; ++i) {
        unsigned long long best = ~0ull;
        #pragma unroll
        for (int j = 0; j < 8; ++j) {
            float sq = rT[i] + cT[j] - 2.0f * acc[i][j] + de2;
            sq = fmaxf(sq, 0.0f);
            float dist = sqrtf(sq);
            unsigned long long key =
                ((unsigned long long)__float_as_uint(dist) << 32) |
                (unsigned int)(cb + tx * 8 + j);
            best = umin64(best, key);
        }
        #pragma unroll
        for (int msk = 1; msk <= 8; msk <<= 1) {
            unsigned long long o = __shfl_xor((long long)best, msk, 64);
            best = umin64(best, (unsigned long long)o);
        }
        if (tx == 0) atomicMin(&keys[rb + ty * 8 + i], best);
    }
}

// ---------- finalize: 8 blocks of 256 rows ----------
__global__ void finalize(const unsigned long long* __restrict__ keys,
                         const float* __restrict__ loc,
                         float* __restrict__ out)
{
    int t = threadIdx.x;
    int r = blockIdx.x * 256 + t;
    unsigned long long k = keys[r];
    unsigned int idx = (unsigned int)(k & 0xFFFFFFFFu);
    float dist = __uint_as_float((unsigned int)(k >> 32));
    out[r] = (float)idx;
    out[B_ + 2 * r]     = loc[2 * idx];
    out[B_ + 2 * r + 1] = loc[2 * idx + 1];
    float sum = dist;
    for (int off = 32; off; off >>= 1) sum += __shfl_down(sum, off, 64);
    __shared__ float s[4];
    if ((t & 63) == 0) s[t >> 6] = sum;
    __syncthreads();
    if (t == 0) atomicAdd(&out[3 * B_], (s[0] + s[1] + s[2] + s[3]) / (float)B_);
}

extern "C" void kernel_launch(void* const* d_in, const int* in_sizes, int n_in,
                              void* d_out, int out_size, void* d_ws, size_t ws_size,
                              hipStream_t stream)
{
    const float* x   = (const float*)d_in[0];
    const float* w   = (const float*)d_in[1];
    const float* loc = (const float*)d_in[2];
    float* out = (float*)d_out;

    char* ws = (char*)d_ws;
    unsigned long long* keys = (unsigned long long*)ws;   // 16 KB
    float* rowTerm = (float*)(ws + (16 << 10));           //  8 KB
    float* colTerm = (float*)(ws + (24 << 10));           // 64 KB
    _Float16* xh  = (_Float16*)(ws + (1ull << 20));       //  4 MB
    _Float16* xl  = (_Float16*)(ws + (5ull << 20));       //  4 MB
    _Float16* wth = (_Float16*)(ws + (9ull << 20));       // 32 MB
    _Float16* wtl = (_Float16*)(ws + (41ull << 20));      // 32 MB
    const size_t NEED = 74ull << 20;  // +1 MB tail pad for prefetch over-read

    hipMemsetAsync(keys, 0xFF, B_ * sizeof(unsigned long long), stream);
    hipMemsetAsync(colTerm, 0, M_ * sizeof(float), stream);
    hipMemsetAsync(out + 3 * B_, 0, sizeof(float), stream);

    if (ws_size >= NEED) {
        xconv<<<B_, 256, 0, stream>>>(x, xh, xl, rowTerm);
        wconv<<<dim3(M_ / 64, D_ / 64), 256, 0, stream>>>(w, wth, wtl, colTerm);
        som_mfma<<<2048, 256, 0, stream>>>(
            xh, xl, wth, wtl, rowTerm, colTerm, keys);
    } else {
        row_stats<<<B_, 256, 0, stream>>>(x, rowTerm);
        col_stats<<<dim3(M_ / 256, D_ / 64), 256, 0, stream>>>(w, colTerm);
        som_gemm<<<dim3(M_ / 128, B_ / 128), 256, 0, stream>>>(
            x, w, rowTerm, colTerm, keys);
    }
    finalize<<<8, 256, 0, stream>>>(keys, loc, out);
}

// Round 8
// 310.923 us; speedup vs baseline: 1.3257x; 1.1074x over previous
//
#include <hip/hip_runtime.h>
#include <cstdint>
#include <cstddef>

// SOM BMU: dists[b,m] = ||x[b] - W[:,m] + eps||, argmin/min over m.
//   sq = rowTerm[b] + colTerm[m] - 2*dot(x[b],W[:,m]) + D*eps^2
// dot via split-precision f16 MFMA (xh.wh + xh.wl + xl.wh, ~2^-22 rel err).
// R8: 128x256 block tile (96 MFMA/wave/iter -> barrier drain amortized 8x),
// GLDS staging with PRE-SWIZZLED storage format written by the prep pass:
//   addr16(r,c) = (r>>4)*32768 + (c>>2)*1024 + (c&3)*256 + (r&15)*16
// -> staging is linear lane-order (coalesced 1KB/wave), fragment
// ds_read_b128 has each 16-lane group on 16 consecutive slots (conflict-
// free per R7 measurement). All prep fused into ONE kernel (3 launches).
// Argmin via packed u64 key (dist_bits<<32 | m) + atomicMin.

#define B_  2048
#define D_  1024
#define M_  16384
#define EPS_ 1e-6f

typedef _Float16 v8h __attribute__((ext_vector_type(8)));
typedef float    v4f __attribute__((ext_vector_type(4)));

static __device__ __forceinline__ unsigned long long umin64(unsigned long long a,
                                                            unsigned long long b) {
    return a < b ? a : b;
}

// swizzled 16B-chunk address: row r, k-chunk c (8 f16 per chunk)
static __device__ __forceinline__ size_t addr16(int r, int c) {
    return (size_t)(r >> 4) * 32768 + (size_t)(c >> 2) * 1024 +
           (size_t)(c & 3) * 256 + (size_t)(r & 15) * 16;
}

#define GLDS16(g, l)                                                            \
    __builtin_amdgcn_global_load_lds(                                           \
        (const __attribute__((address_space(1))) void*)(g),                     \
        (__attribute__((address_space(3))) void*)(l), 16, 0, 0)

// ---------- fused prep: x->xh/xl + rowTerm, W->wth/wtl + colTerm, inits ----
// blocks 0..255: W cols (64 each, full D). blocks 256..319: x rows (32 each).
// block 320: keys + loss-slot init.
__global__ __launch_bounds__(256) void prep(
    const float* __restrict__ x, const float* __restrict__ W,
    _Float16* __restrict__ xh, _Float16* __restrict__ xl,
    _Float16* __restrict__ wth, _Float16* __restrict__ wtl,
    float* __restrict__ rowTerm, float* __restrict__ colTerm,
    unsigned long long* __restrict__ keys, float* __restrict__ out)
{
    const int t = threadIdx.x;
    const int blk = blockIdx.x;
    if (blk < 256) {
        __shared__ float tile[64][65];
        __shared__ float colsq[64];
        if (t < 64) colsq[t] = 0.f;
        const int m0 = blk * 64;
        const int dloc = t >> 4, mq = (t & 15) * 4;
        const int m_local = t & 63, cp = t >> 6;   // cp == wave id
        for (int dt = 0; dt < 16; ++dt) {
            const int d0 = dt * 64;
            __syncthreads();  // guards tile overwrite (and colsq init, dt=0)
            #pragma unroll
            for (int s = 0; s < 4; ++s) {
                float4 v = *(const float4*)(W + (size_t)(d0 + dloc + 16 * s) * M_ + m0 + mq);
                tile[dloc + 16 * s][mq + 0] = v.x;
                tile[dloc + 16 * s][mq + 1] = v.y;
                tile[dloc + 16 * s][mq + 2] = v.z;
                tile[dloc + 16 * s][mq + 3] = v.w;
            }
            __syncthreads();
            v8h h0, l0, h1, l1;
            float part = 0.f;
            #pragma unroll
            for (int e = 0; e < 8; ++e) {
                float v = tile[16 * cp + e][m_local];
                _Float16 hi = (_Float16)v;
                h0[e] = hi; l0[e] = (_Float16)(v - (float)hi);
                part += v * v - 2.0f * EPS_ * v;
            }
            #pragma unroll
            for (int e = 0; e < 8; ++e) {
                float v = tile[16 * cp + 8 + e][m_local];
                _Float16 hi = (_Float16)v;
                h1[e] = hi; l1[e] = (_Float16)(v - (float)hi);
                part += v * v - 2.0f * EPS_ * v;
            }
            atomicAdd(&colsq[m_local], part);
            const int m  = m0 + m_local;
            const int c0 = dt * 8 + 2 * cp;
            const size_t a0 = addr16(m, c0), a1 = addr16(m, c0 + 1);
            *(v8h*)((char*)wth + a0) = h0; *(v8h*)((char*)wth + a1) = h1;
            *(v8h*)((char*)wtl + a0) = l0; *(v8h*)((char*)wtl + a1) = l1;
        }
        __syncthreads();
        if (t < 64) colTerm[m0 + t] = colsq[t];
    } else if (blk < 320) {
        __shared__ float rsum[2];
        const int rb0 = (blk - 256) * 32;
        for (int p = 0; p < 16; ++p) {
            if (t < 2) rsum[t] = 0.f;
            __syncthreads();
            const int r = rb0 + 2 * p + (t >> 7);
            const int c = t & 127;
            float4 q1 = *(const float4*)(x + (size_t)r * D_ + 8 * c);
            float4 q2 = *(const float4*)(x + (size_t)r * D_ + 8 * c + 4);
            float vv[8] = {q1.x, q1.y, q1.z, q1.w, q2.x, q2.y, q2.z, q2.w};
            v8h h, l;
            float part = 0.f;
            #pragma unroll
            for (int e = 0; e < 8; ++e) {
                _Float16 hi = (_Float16)vv[e];
                h[e] = hi; l[e] = (_Float16)(vv[e] - (float)hi);
                part += vv[e] * vv[e] + 2.0f * EPS_ * vv[e];
            }
            const size_t a = addr16(r, c);
            *(v8h*)((char*)xh + a) = h;
            *(v8h*)((char*)xl + a) = l;
            for (int off = 32; off; off >>= 1) part += __shfl_down(part, off, 64);
            if ((t & 63) == 0) atomicAdd(&rsum[t >> 7], part);
            __syncthreads();
            if ((t & 127) == 0) rowTerm[r] = rsum[t >> 7];
            __syncthreads();
        }
    } else {
        for (int i = t; i < B_; i += 256) keys[i] = ~0ull;
        if (t == 0) out[3 * B_] = 0.f;
    }
}

// ---------- main MFMA distance GEMM + argmin ----------
// 128x256 block tile, 4 waves (2x2, each 64 rows x 128 cols), BK=32.
__global__ __launch_bounds__(256, 2) void som_mfma(
    const _Float16* __restrict__ xh, const _Float16* __restrict__ xl,
    const _Float16* __restrict__ wth, const _Float16* __restrict__ wtl,
    const float* __restrict__ rowTerm, const float* __restrict__ colTerm,
    unsigned long long* __restrict__ keys)
{
    __shared__ __align__(16) char smem[49152];   // Ah 8K | Al 8K | Bh 16K | Bl 16K
    _Float16* Ah = (_Float16*)smem;
    _Float16* Al = (_Float16*)(smem + 8192);
    _Float16* Bh = (_Float16*)(smem + 16384);
    _Float16* Bl = (_Float16*)(smem + 32768);

    const int t = threadIdx.x;
    const int g = blockIdx.x;
    const int cb = (g >> 4) * 256;   // consecutive blocks share the B-slab
    const int rb = (g & 15) * 128;
    const int L = t & 63, w = t >> 6;
    const int wro = (w >> 1) * 64;
    const int wco = (w & 1) * 128;
    const int c16 = L & 15, kq = L >> 4;

    // staging: per call, wave wgrp covers one 16-row group (1 KB linear)
    const int wgrp = t >> 6;
    const int lane16 = (t & 63) * 16;
    const int ldsw = wgrp * 1024;                 // wave-uniform LDS base
    const size_t abase0 = (size_t)((rb >> 4) + wgrp) * 32768 + lane16;
    const size_t abase1 = abase0 + 4ull * 32768;
    const size_t bbase0 = (size_t)((cb >> 4) + wgrp) * 32768 + lane16;
    const size_t bbase1 = bbase0 + 4ull * 32768;
    const size_t bbase2 = bbase0 + 8ull * 32768;
    const size_t bbase3 = bbase0 + 12ull * 32768;

    const char* pxh = (const char*)xh;
    const char* pxl = (const char*)xl;
    const char* pwh = (const char*)wth;
    const char* pwl = (const char*)wtl;

    v4f acc[4][8];
    #pragma unroll
    for (int i = 0; i < 4; ++i)
        #pragma unroll
        for (int j = 0; j < 8; ++j) acc[i][j] = (v4f){0.f, 0.f, 0.f, 0.f};

    // fragment read offsets (f16 units): group grp -> grp*512 + lofs
    // lofs: chunk (L>>4)*128 + row (L&15)*8 -> 16-lane groups on 16
    // consecutive slots (conflict-free)
    const int lofs = kq * 128 + c16 * 8;
    int ia[4], ibx[8];
    #pragma unroll
    for (int i = 0; i < 4; ++i) ia[i] = ((wro >> 4) + i) * 512 + lofs;
    #pragma unroll
    for (int j = 0; j < 8; ++j) ibx[j] = ((wco >> 4) + j) * 512 + lofs;

    for (int S = 0; S < 32; ++S) {
        const size_t ko = (size_t)S * 1024;
        __syncthreads();
        GLDS16(pxh + abase0 + ko, smem + ldsw);
        GLDS16(pxh + abase1 + ko, smem + 4096 + ldsw);
        GLDS16(pxl + abase0 + ko, smem + 8192 + ldsw);
        GLDS16(pxl + abase1 + ko, smem + 12288 + ldsw);
        GLDS16(pwh + bbase0 + ko, smem + 16384 + ldsw);
        GLDS16(pwh + bbase1 + ko, smem + 20480 + ldsw);
        GLDS16(pwh + bbase2 + ko, smem + 24576 + ldsw);
        GLDS16(pwh + bbase3 + ko, smem + 28672 + ldsw);
        GLDS16(pwl + bbase0 + ko, smem + 32768 + ldsw);
        GLDS16(pwl + bbase1 + ko, smem + 36864 + ldsw);
        GLDS16(pwl + bbase2 + ko, smem + 40960 + ldsw);
        GLDS16(pwl + bbase3 + ko, smem + 45056 + ldsw);
        __syncthreads();

        v8h ah[4], al4[4], bh4[4], bl4[4];
        #pragma unroll
        for (int i = 0; i < 4; ++i) {
            ah[i]  = *(const v8h*)(Ah + ia[i]);
            al4[i] = *(const v8h*)(Al + ia[i]);
        }
        #pragma unroll
        for (int j = 0; j < 4; ++j) {
            bh4[j] = *(const v8h*)(Bh + ibx[j]);
            bl4[j] = *(const v8h*)(Bl + ibx[j]);
        }
        #pragma unroll
        for (int i = 0; i < 4; ++i)
            #pragma unroll
            for (int j = 0; j < 4; ++j) {
                acc[i][j] = __builtin_amdgcn_mfma_f32_16x16x32_f16(ah[i],  bh4[j], acc[i][j], 0, 0, 0);
                acc[i][j] = __builtin_amdgcn_mfma_f32_16x16x32_f16(ah[i],  bl4[j], acc[i][j], 0, 0, 0);
                acc[i][j] = __builtin_amdgcn_mfma_f32_16x16x32_f16(al4[i], bh4[j], acc[i][j], 0, 0, 0);
            }
        #pragma unroll
        for (int j = 0; j < 4; ++j) {
            bh4[j] = *(const v8h*)(Bh + ibx[j + 4]);
            bl4[j] = *(const v8h*)(Bl + ibx[j + 4]);
        }
        #pragma unroll
        for (int i = 0; i < 4; ++i)
            #pragma unroll
            for (int j = 0; j < 4; ++j) {
                acc[i][j+4] = __builtin_amdgcn_mfma_f32_16x16x32_f16(ah[i],  bh4[j], acc[i][j+4], 0, 0, 0);
                acc[i][j+4] = __builtin_amdgcn_mfma_f32_16x16x32_f16(ah[i],  bl4[j], acc[i][j+4], 0, 0, 0);
                acc[i][j+4] = __builtin_amdgcn_mfma_f32_16x16x32_f16(al4[i], bh4[j], acc[i][j+4], 0, 0, 0);
            }
    }

    // epilogue: C/D layout col=lane&15, row=(lane>>4)*4+reg  [verified m89/m91]
    float cT[8];
    #pragma unroll
    for (int j = 0; j < 8; ++j) cT[j] = colTerm[cb + wco + j * 16 + c16];
    const float de2 = (float)D_ * EPS_ * EPS_;
    #pragma unroll
    for (int i = 0; i < 4; ++i) {
        #pragma unroll
        for (int r = 0; r < 4; ++r) {
            int row_g = rb + wro + i * 16 + kq * 4 + r;
            float rt = rowTerm[row_g];
            unsigned long long best = ~0ull;
            #pragma unroll
            for (int j = 0; j < 8; ++j) {
                float sq = rt + cT[j] - 2.0f * acc[i][j][r] + de2;
                sq = fmaxf(sq, 0.0f);
                float dist = sqrtf(sq);
                unsigned long long key =
                    ((unsigned long long)__float_as_uint(dist) << 32) |
                    (unsigned int)(cb + wco + j * 16 + c16);
                best = umin64(best, key);
            }
            #pragma unroll
            for (int m = 1; m <= 8; m <<= 1) {
                unsigned long long o =
                    (unsigned long long)__shfl_xor((long long)best, m, 64);
                best = umin64(best, o);
            }
            if (c16 == 0) atomicMin(&keys[row_g], best);
        }
    }
}

// ---------- fallback fp32 path (used only if ws too small) ----------
__global__ void row_stats(const float* __restrict__ x, float* __restrict__ rowTerm) {
    int b = blockIdx.x;
    const float* xr = x + (size_t)b * D_;
    int t = threadIdx.x;
    float acc = 0.f;
    for (int i = t; i < D_; i += 256) {
        float v = xr[i];
        acc += v * v + 2.0f * EPS_ * v;
    }
    for (int off = 32; off; off >>= 1) acc += __shfl_down(acc, off, 64);
    __shared__ float s[4];
    if ((t & 63) == 0) s[t >> 6] = acc;
    __syncthreads();
    if (t == 0) rowTerm[b] = s[0] + s[1] + s[2] + s[3];
}

__global__ void col_stats(const float* __restrict__ w, float* __restrict__ colTerm) {
    int m = blockIdx.x * 256 + threadIdx.x;
    int d0 = blockIdx.y * 64;
    const float* p = w + (size_t)d0 * M_ + m;
    float acc = 0.f;
    #pragma unroll 8
    for (int d = 0; d < 64; ++d) {
        float v = p[(size_t)d * M_];
        acc += v * v - 2.0f * EPS_ * v;
    }
    atomicAdd(&colTerm[m], acc);
}

__global__ __launch_bounds__(256, 2) void som_gemm(
    const float* __restrict__ A, const float* __restrict__ Wt,
    const float* __restrict__ rowTerm, const float* __restrict__ colTerm,
    unsigned long long* __restrict__ keys)
{
    __shared__ float As[8][128];
    __shared__ float Bs[8][128];
    const int t  = threadIdx.x;
    const int rb = blockIdx.y * 128;
    const int cb = blockIdx.x * 128;
    const int tx = t & 15;
    const int ty = t >> 4;
    float acc[8][8];
    #pragma unroll
    for (int i = 0; i < 8; ++i)
        #pragma unroll
        for (int j = 0; j < 8; ++j) acc[i][j] = 0.f;
    const int la_row = t >> 1, la_k = (t & 1) * 4;
    const int lb_k = t >> 5, lb_n = (t & 31) * 4;
    const float* Aptr = A + (size_t)(rb + la_row) * D_ + la_k;
    const float* Bptr = Wt + (size_t)lb_k * M_ + cb + lb_n;
    for (int k0 = 0; k0 < D_; k0 += 8) {
        float4 av = *(const float4*)(Aptr + k0);
        float4 bv = *(const float4*)(Bptr + (size_t)k0 * M_);
        __syncthreads();
        As[la_k + 0][la_row] = av.x;
        As[la_k + 1][la_row] = av.y;
        As[la_k + 2][la_row] = av.z;
        As[la_k + 3][la_row] = av.w;
        *(float4*)&Bs[lb_k][lb_n] = bv;
        __syncthreads();
        #pragma unroll
        for (int k = 0; k < 8; ++k) {
            float a[8], b[8];
            #pragma unroll
            for (int i = 0; i < 8; ++i) a[i] = As[k][ty * 8 + i];
            #pragma unroll
            for (int j = 0; j < 8; ++j) b[j] = Bs[k][tx * 8 + j];
            #pragma unroll
            for (int i = 0; i < 8; ++i)
                #pragma unroll
                for (int j = 0; j < 8; ++j) acc[i][j] += a[i] * b[j];
        }
    }
    float rT[8], cT[8];
    #pragma unroll
    for (int i = 0; i < 8; ++i) rT[i] = rowTerm[rb + ty * 8 + i];
    #pragma unroll
    for (int j = 0; j < 8; ++j) cT[j] = colTerm[cb + tx * 8 + j];
    const float de2 = (float)D_ * EPS_ * EPS_;
    #pragma unroll
    for (int i = 0; i < 8; ++i) {
        unsigned long long best = ~0ull;
        #pragma unroll
        for (int j = 0; j < 8; ++j) {
            float sq = rT[i] + cT[j] - 2.0f * acc[i][j] + de2;
            sq = fmaxf(sq, 0.0f);
            float dist = sqrtf(sq);
            unsigned long long key =
                ((unsigned long long)__float_as_uint(dist) << 32) |
                (unsigned int)(cb + tx * 8 + j);
            best = umin64(best, key);
        }
        #pragma unroll
        for (int msk = 1; msk <= 8; msk <<= 1) {
            unsigned long long o = __shfl_xor((long long)best, msk, 64);
            best = umin64(best, (unsigned long long)o);
        }
        if (tx == 0) atomicMin(&keys[rb + ty * 8 + i], best);
    }
}

// ---------- finalize: 8 blocks of 256 rows ----------
__global__ void finalize(const unsigned long long* __restrict__ keys,
                         const float* __restrict__ loc,
                         float* __restrict__ out)
{
    int t = threadIdx.x;
    int r = blockIdx.x * 256 + t;
    unsigned long long k = keys[r];
    unsigned int idx = (unsigned int)(k & 0xFFFFFFFFu);
    float dist = __uint_as_float((unsigned int)(k >> 32));
    out[r] = (float)idx;
    out[B_ + 2 * r]     = loc[2 * idx];
    out[B_ + 2 * r + 1] = loc[2 * idx + 1];
    float sum = dist;
    for (int off = 32; off; off >>= 1) sum += __shfl_down(sum, off, 64);
    __shared__ float s[4];
    if ((t & 63) == 0) s[t >> 6] = sum;
    __syncthreads();
    if (t == 0) atomicAdd(&out[3 * B_], (s[0] + s[1] + s[2] + s[3]) / (float)B_);
}

extern "C" void kernel_launch(void* const* d_in, const int* in_sizes, int n_in,
                              void* d_out, int out_size, void* d_ws, size_t ws_size,
                              hipStream_t stream)
{
    const float* x   = (const float*)d_in[0];
    const float* w   = (const float*)d_in[1];
    const float* loc = (const float*)d_in[2];
    float* out = (float*)d_out;

    char* ws = (char*)d_ws;
    unsigned long long* keys = (unsigned long long*)ws;   // 16 KB
    float* rowTerm = (float*)(ws + (16 << 10));           //  8 KB
    float* colTerm = (float*)(ws + (24 << 10));           // 64 KB
    _Float16* xh  = (_Float16*)(ws + (1ull << 20));       //  4 MB
    _Float16* xl  = (_Float16*)(ws + (5ull << 20));       //  4 MB
    _Float16* wth = (_Float16*)(ws + (9ull << 20));       // 32 MB
    _Float16* wtl = (_Float16*)(ws + (41ull << 20));      // 32 MB
    const size_t NEED = 73ull << 20;

    if (ws_size >= NEED) {
        prep<<<321, 256, 0, stream>>>(x, w, xh, xl, wth, wtl,
                                      rowTerm, colTerm, keys, out);
        som_mfma<<<1024, 256, 0, stream>>>(
            xh, xl, wth, wtl, rowTerm, colTerm, keys);
    } else {
        hipMemsetAsync(keys, 0xFF, B_ * sizeof(unsigned long long), stream);
        hipMemsetAsync(colTerm, 0, M_ * sizeof(float), stream);
        hipMemsetAsync(out + 3 * B_, 0, sizeof(float), stream);
        row_stats<<<B_, 256, 0, stream>>>(x, rowTerm);
        col_stats<<<dim3(M_ / 256, D_ / 64), 256, 0, stream>>>(w, colTerm);
        som_gemm<<<dim3(M_ / 128, B_ / 128), 256, 0, stream>>>(
            x, w, rowTerm, colTerm, keys);
    }
    finalize<<<8, 256, 0, stream>>>(keys, loc, out);
}